// Round 15
// baseline (86.433 us; speedup 1.0000x reference)
//
#include <hip/hip_runtime.h>

#define NVEC (64*64*64)   // 262144 vectors
#define KCB 1024          // codebook size
#define DIM 64            // codebook dim
#define NSLICE 4          // codebook slices (256 codes each)
#define VSET 1024         // vectors per A-block
#define NBATCH 16         // batches of 64 vectors
#define AGRID (NSLICE * (NVEC / VSET))   // 1024 -> 4 blocks/CU
#define BVEC 256          // vectors per B-block
#define BGRID (NVEC / BVEC)              // 1024
#define NSLOT 32          // global count-accumulation slots

typedef __attribute__((ext_vector_type(8))) short s16x8;   // 8 x bf16
typedef __attribute__((ext_vector_type(4))) float f32x4;

#define MFMA16(A, B, C) __builtin_amdgcn_mfma_f32_16x16x32_bf16((A), (B), (C), 0, 0, 0)

// ws layout (bytes):
//       0 : float cnf[1024]            (ends 4096)
//    4096 : ushort cbA[64][2][64][8]   A-frag bf16(-2c), 131072 B (ends 135168)
//  135168 : uint pbuf[4][NVEC]         packed (score|idx) per slice, 4 MB (ends 4329472)
// 4329472 : float xnpart[1024]         sum ||x||^2 partials (slice-0 waves)
// 4333568 : float scorepart[1024]      per-B-block score sums
// 4337664 : uint slots[32][1024]       count accumulators (zeroed by vq_prep)

__global__ __launch_bounds__(256) void vq_prep(const float* __restrict__ cb,
                                               unsigned short* __restrict__ cbA,
                                               float* __restrict__ cnf,
                                               unsigned int* __restrict__ slots) {
    int q = blockIdx.x * 256 + threadIdx.x;      // 0..8191
    ((int4*)slots)[q] = int4{0, 0, 0, 0};         // zero all 32*1024 uints
    int t = q >> 7;
    int h = (q >> 6) & 1;
    int l = q & 63;
    int m = t * 16 + (l & 15);
    int d0 = h * 32 + ((l >> 4) & 3) * 8;
    const float* row = cb + (size_t)m * DIM + d0;
    unsigned short* dst = cbA + (size_t)q * 8;
    #pragma unroll
    for (int j = 0; j < 8; ++j) {
        float f = -2.0f * row[j];
        unsigned u = __float_as_uint(f);
        dst[j] = (unsigned short)((u + 0x7fffu + ((u >> 16) & 1u)) >> 16);  // RNE bf16
    }
    if (q < KCB) {
        const float* r2 = cb + (size_t)q * DIM;
        double s = 0.0;
        for (int d = 0; d < DIM; ++d) { double c = (double)r2[d]; s = fma(c, c, s); }
        cnf[q] = (float)s;
    }
}

// Phase A: 4-wave blocks (1 wave/SIMD), 4 independent blocks/CU.
// Wave wv holds 64 codes of slice `slice` register-resident; block scores
// 1024 vectors against its 256-code slice; packed best -> pbuf[slice][vec].
__global__ __launch_bounds__(256, 4) void vq_sliceA(const float* __restrict__ inp,
                                                    const unsigned short* __restrict__ cbA,
                                                    const float* __restrict__ cnf,
                                                    unsigned int* __restrict__ pbuf,
                                                    float* __restrict__ xnpart) {
    __shared__ int4  xf[2][512];     // 64-vec bf16 frags, double-buffered, 16 KB
    __shared__ float sred[64][5];    // per-vec per-wave packed best

    const int tid  = threadIdx.x;
    const int lane = tid & 63;
    const int wv   = tid >> 6;       // wave 0..3
    const int l15  = lane & 15;
    const int g    = lane >> 4;
    const int gi   = g * 4;
    const int slice  = blockIdx.x & 3;
    const int vecset = blockIdx.x >> 2;
    const size_t vsbase = (size_t)vecset * VSET;

    // convert role: thread handles vec cv (in batch), dim-quarter cq (16 dims)
    const int cv = tid >> 2, cq = tid & 3;
    const int c0 = ((cv >> 4) * 2 + (cq >> 1)) * 64 + ((cq & 1) * 2) * 16 + (cv & 15);
    const int c1 = c0 + 16;

    // codebook slice -> registers (stays forever)
    const s16x8* __restrict__ Ap = (const s16x8*)cbA;
    s16x8 A[4][2];
    f32x4 cn[4];
    #pragma unroll
    for (int t = 0; t < 4; ++t) {
        int Tg = slice * 16 + wv * 4 + t;          // global 16-code tile
        A[t][0] = Ap[(Tg * 2 + 0) * 64 + lane];
        A[t][1] = Ap[(Tg * 2 + 1) * 64 + lane];
        cn[t]   = *(const f32x4*)(cnf + Tg * 16 + gi);
    }

    // batch-0 x loads (64 B/thread, coalesced)
    const float4* xp = (const float4*)(inp + (vsbase + cv) * DIM + cq * 16);
    float4 xr0 = xp[0], xr1 = xp[1], xr2 = xp[2], xr3 = xp[3];
    float xnacc = 0.f;

    for (int b = 0; b < NBATCH; ++b) {
        const int buf = b & 1;

        // ---- convert 16 floats -> 2 LDS frag cells; accumulate ||x||^2 ----
        {
            float f0 = xr0.x, f1 = xr0.y, f2 = xr0.z, f3 = xr0.w;
            float f4 = xr1.x, f5 = xr1.y, f6 = xr1.z, f7 = xr1.w;
            float f8 = xr2.x, f9 = xr2.y, f10 = xr2.z, f11 = xr2.w;
            float f12 = xr3.x, f13 = xr3.y, f14 = xr3.z, f15 = xr3.w;
            xnacc = fmaf(f0, f0, xnacc);   xnacc = fmaf(f1, f1, xnacc);
            xnacc = fmaf(f2, f2, xnacc);   xnacc = fmaf(f3, f3, xnacc);
            xnacc = fmaf(f4, f4, xnacc);   xnacc = fmaf(f5, f5, xnacc);
            xnacc = fmaf(f6, f6, xnacc);   xnacc = fmaf(f7, f7, xnacc);
            xnacc = fmaf(f8, f8, xnacc);   xnacc = fmaf(f9, f9, xnacc);
            xnacc = fmaf(f10, f10, xnacc); xnacc = fmaf(f11, f11, xnacc);
            xnacc = fmaf(f12, f12, xnacc); xnacc = fmaf(f13, f13, xnacc);
            xnacc = fmaf(f14, f14, xnacc); xnacc = fmaf(f15, f15, xnacc);
            unsigned w0, w1, w2, w3, w4, w5, w6, w7;
            asm("v_cvt_pk_bf16_f32 %0, %1, %2" : "=v"(w0) : "v"(f0),  "v"(f1));
            asm("v_cvt_pk_bf16_f32 %0, %1, %2" : "=v"(w1) : "v"(f2),  "v"(f3));
            asm("v_cvt_pk_bf16_f32 %0, %1, %2" : "=v"(w2) : "v"(f4),  "v"(f5));
            asm("v_cvt_pk_bf16_f32 %0, %1, %2" : "=v"(w3) : "v"(f6),  "v"(f7));
            asm("v_cvt_pk_bf16_f32 %0, %1, %2" : "=v"(w4) : "v"(f8),  "v"(f9));
            asm("v_cvt_pk_bf16_f32 %0, %1, %2" : "=v"(w5) : "v"(f10), "v"(f11));
            asm("v_cvt_pk_bf16_f32 %0, %1, %2" : "=v"(w6) : "v"(f12), "v"(f13));
            asm("v_cvt_pk_bf16_f32 %0, %1, %2" : "=v"(w7) : "v"(f14), "v"(f15));
            xf[buf][c0] = int4{(int)w0, (int)w1, (int)w2, (int)w3};
            xf[buf][c1] = int4{(int)w4, (int)w5, (int)w6, (int)w7};
        }
        __syncthreads();   // frags ready

        // issue next batch's x loads; held in regs across MFMA phase
        if (b + 1 < NBATCH) {
            const float4* np = (const float4*)(inp + (vsbase + (size_t)(b + 1) * 64 + cv) * DIM + cq * 16);
            xr0 = np[0]; xr1 = np[1]; xr2 = np[2]; xr3 = np[3];
        }

        // ---- MFMA + argmin: 64 vecs x this wave's 64 codes ----
        #pragma unroll
        for (int vt = 0; vt < 4; ++vt) {
            s16x8 xb0 = *(const s16x8*)&xf[buf][(vt * 2 + 0) * 64 + lane];
            s16x8 xb1 = *(const s16x8*)&xf[buf][(vt * 2 + 1) * 64 + lane];
            f32x4 a0 = cn[0], a1 = cn[1], a2 = cn[2], a3 = cn[3];
            a0 = MFMA16(A[0][0], xb0, a0);
            a1 = MFMA16(A[1][0], xb0, a1);
            a2 = MFMA16(A[2][0], xb0, a2);
            a3 = MFMA16(A[3][0], xb0, a3);
            a0 = MFMA16(A[0][1], xb1, a0);
            a1 = MFMA16(A[1][1], xb1, a1);
            a2 = MFMA16(A[2][1], xb1, a2);
            a3 = MFMA16(A[3][1], xb1, a3);

            float bv = 3.4e38f;
            #define PACKMIN(ACC, TT) {                                                          \
                unsigned cbase = (unsigned)((slice * 16 + wv * 4 + (TT)) * 16 + gi);            \
                float p0 = __uint_as_float((__float_as_uint(ACC[0]) & 0xFFFFFC00u) | cbase);    \
                float p1 = __uint_as_float((__float_as_uint(ACC[1]) & 0xFFFFFC00u) | (cbase+1));\
                float p2 = __uint_as_float((__float_as_uint(ACC[2]) & 0xFFFFFC00u) | (cbase+2));\
                float p3 = __uint_as_float((__float_as_uint(ACC[3]) & 0xFFFFFC00u) | (cbase+3));\
                float m01;                                                                      \
                asm("v_min3_f32 %0, %1, %2, %3" : "=v"(m01) : "v"(p0), "v"(p1), "v"(p2));       \
                asm("v_min3_f32 %0, %1, %2, %3" : "=v"(bv) : "v"(m01), "v"(p3), "v"(bv)); }
            PACKMIN(a0, 0) PACKMIN(a1, 1) PACKMIN(a2, 2) PACKMIN(a3, 3)
            #undef PACKMIN
            bv = fminf(bv, __shfl_xor(bv, 16));
            bv = fminf(bv, __shfl_xor(bv, 32));
            if (g == 0) sred[vt * 16 + l15][wv] = bv;
        }
        __syncthreads();   // sred ready

        // ---- cross-wave combine (4 waves) + compacted coalesced pbuf write ----
        {
            const int v = tid >> 2, slot = tid & 3;
            float pb = sred[v][slot];
            pb = fminf(pb, __shfl_xor(pb, 1));
            pb = fminf(pb, __shfl_xor(pb, 2));
            float pbc = __shfl(pb, (lane & 15) * 4);   // lanes 0-15 <- vec wv*16+lane
            if (lane < 16)
                pbuf[(size_t)slice * NVEC + vsbase + (size_t)b * 64 + wv * 16 + lane] =
                    __float_as_uint(pbc);
        }
        // next convert writes xf[buf^1]; sred rewritten only after next barrier
    }

    // ---- sum ||x||^2 partials (slice-0 blocks cover every vector once) ----
    if (slice == 0) {
        float v = xnacc;
        #pragma unroll
        for (int off = 32; off > 0; off >>= 1) v += __shfl_xor(v, off);
        if (lane == 0) xnpart[vecset * 4 + wv] = v;
    }
}

// Phase B: streaming combine -- min over 4 slices, gather code row, write out,
// LDS hist -> slots. No MFMA, no lockstep; pure TLP.
__global__ __launch_bounds__(256) void vq_sliceB(const unsigned int* __restrict__ pbuf,
                                                 const float* __restrict__ cb,
                                                 float* __restrict__ out,
                                                 float* __restrict__ scorepart,
                                                 unsigned int* __restrict__ slots) {
    __shared__ unsigned int histS[KCB];
    __shared__ float lred[4];
    const int tid = threadIdx.x, lane = tid & 63, wv = tid >> 6;
    #pragma unroll
    for (int i = 0; i < 4; ++i) histS[tid + i * 256] = 0u;
    __syncthreads();

    float sacc = 0.f;
    const size_t vb = (size_t)blockIdx.x * BVEC;
    const float4* cb4 = (const float4*)cb;
    float4* out4 = (float4*)out;

    for (int r = 0; r < BVEC / 16; ++r) {
        const size_t vec = vb + r * 16 + (tid >> 4);
        const int sl = tid & 15;
        float pf = __uint_as_float(pbuf[(size_t)(sl & 3) * NVEC + vec]);
        pf = fminf(pf, __shfl_xor(pf, 1));
        pf = fminf(pf, __shfl_xor(pf, 2));      // all 16 lanes hold the 4-slice min
        const int bk = (int)(__float_as_uint(pf) & 1023u);
        float4 q = cb4[bk * 16 + sl];
        out4[vec * 16 + sl] = q;
        if (sl == 0) {
            sacc += pf;                          // score sum (idx-bit noise ~2e-6 rel)
            atomicAdd(&histS[bk], 1u);
        }
    }

    #pragma unroll
    for (int off = 32; off > 0; off >>= 1) sacc += __shfl_xor(sacc, off);
    if (lane == 0) lred[wv] = sacc;
    __syncthreads();
    if (tid == 0) scorepart[blockIdx.x] = lred[0] + lred[1] + lred[2] + lred[3];
    #pragma unroll
    for (int i = 0; i < 4; ++i) {
        unsigned hv = histS[tid + i * 256];
        if (hv) atomicAdd(&slots[(blockIdx.x & (NSLOT - 1)) * KCB + tid + i * 256], hv);
    }
}

__global__ __launch_bounds__(1024) void vq_finalize(float* __restrict__ out,
                                                    const float* __restrict__ scorepart,
                                                    const float* __restrict__ xnpart,
                                                    const unsigned int* __restrict__ slots) {
    __shared__ double red[1024];
    const int tid = threadIdx.x;
    unsigned tot = 0;
    #pragma unroll
    for (int s = 0; s < NSLOT; ++s) tot += slots[s * KCB + tid];
    double p = (double)tot / (double)NVEC;
    double h = p * log(p + 1e-10);
    double ls = (double)scorepart[tid] + (double)xnpart[tid];

    red[tid] = ls;
    __syncthreads();
    for (int t = 512; t > 0; t >>= 1) {
        if (tid < t) red[tid] += red[tid + t];
        __syncthreads();
    }
    double loss_tot = red[0];
    __syncthreads();
    red[tid] = h;
    __syncthreads();
    for (int t = 512; t > 0; t >>= 1) {
        if (tid < t) red[tid] += red[tid + t];
        __syncthreads();
    }
    if (tid == 0) {
        out[(size_t)NVEC * DIM]     = (float)(0.25 * loss_tot / (double)((size_t)NVEC * DIM));
        out[(size_t)NVEC * DIM + 1] = (float)exp(-red[0]);
    }
}

extern "C" void kernel_launch(void* const* d_in, const int* in_sizes, int n_in,
                              void* d_out, int out_size, void* d_ws, size_t ws_size,
                              hipStream_t stream) {
    const float* inp = (const float*)d_in[0];   // (64,64,64,64) f32
    const float* cb  = (const float*)d_in[1];   // (1024,64) f32
    float* out = (float*)d_out;

    char* ws = (char*)d_ws;
    float*          cnf       = (float*)(ws + 0);
    unsigned short* cbA       = (unsigned short*)(ws + 4096);
    unsigned int*   pbuf      = (unsigned int*)(ws + 135168);
    float*          xnpart    = (float*)(ws + 4329472);
    float*          scorepart = (float*)(ws + 4333568);
    unsigned int*   slots     = (unsigned int*)(ws + 4337664);

    vq_prep<<<dim3(32), dim3(256), 0, stream>>>(cb, cbA, cnf, slots);
    vq_sliceA<<<dim3(AGRID), dim3(256), 0, stream>>>(inp, cbA, cnf, pbuf, xnpart);
    vq_sliceB<<<dim3(BGRID), dim3(256), 0, stream>>>(pbuf, cb, out, scorepart, slots);
    vq_finalize<<<dim3(1), dim3(1024), 0, stream>>>(out, scorepart, xnpart, slots);
}